// Round 9
// baseline (315.176 us; speedup 1.0000x reference)
//
#include <hip/hip_runtime.h>

typedef unsigned short u16;
typedef __attribute__((ext_vector_type(8))) short bf16x8;   // 8 bf16 in 4 VGPRs
typedef __attribute__((ext_vector_type(4))) float f32x4;
typedef __attribute__((ext_vector_type(4))) unsigned int u32x4;

#define DIM 2048

__device__ inline u16 f2bf(float f) {
    unsigned u = __builtin_bit_cast(unsigned, f);
    u = (u + 0x7FFFu + ((u >> 16) & 1u)) >> 16;   // RNE, finite inputs only
    return (u16)u;
}

__device__ inline void gl_lds16(const void* g, void* l) {
    __builtin_amdgcn_global_load_lds(
        (const __attribute__((address_space(1))) unsigned int*)g,
        (__attribute__((address_space(3))) unsigned int*)l, 16, 0, 0);
}

struct c32 { float x, y; };
__device__ inline c32 cmul(c32 a, c32 b) { return {a.x*b.x - a.y*b.y, a.x*b.y + a.y*b.x}; }

__device__ inline int slotf(int i) { return i + (i >> 5); }   // bank-pad layout

// ---------------------------------------------------------------------------
// Kernel 1: build T = U^T, one column per block, statevector in LDS.
// (p,p+6) qubit pairing + padded layout + single buffer. Validated round 8.
// ---------------------------------------------------------------------------
__global__ __launch_bounds__(256) void build_ut(const float* __restrict__ w,
                                                u16* __restrict__ ut_re,
                                                u16* __restrict__ ut_im) {
    __shared__ alignas(16) float gre[55][4], gim[55][4];
    __shared__ alignas(16) float G4r[5][5][16], G4i[5][5][16];
    __shared__ alignas(16) u16 ptab[DIM];                 // slot(perm(e)), by e
    __shared__ alignas(16) float vr[DIM + (DIM >> 5)], vi[DIM + (DIM >> 5)];
    const int tid = threadIdx.x;
    const int col = blockIdx.x;

    if (tid < 55) {
        const int layer = tid / 11, q = tid - layer * 11;
        const float WM = 0.63245553203367586f;   // sqrt(2)*5^-0.5
        float hx = 0.5f * WM * w[33*layer + q];
        float hy = 0.5f * WM * w[33*layer + 11 + q];
        float hz = 0.5f * WM * w[33*layer + 22 + q];
        float cx = cosf(hx), sx = sinf(hx);
        float cy = cosf(hy), sy = sinf(hy);
        float cz = cosf(hz), sz = sinf(hz);
        c32 m00{cy*cx,  sy*sx}, m01{-sy*cx, -cy*sx};
        c32 m10{sy*cx, -cy*sx}, m11{ cy*cx, -sy*sx};
        c32 em{cz, -sz}, ep{cz, sz};
        c32 r0 = cmul(em, m00), r1 = cmul(em, m01);
        c32 r2 = cmul(ep, m10), r3 = cmul(ep, m11);
        gre[tid][0] = r0.x; gim[tid][0] = r0.y;
        gre[tid][1] = r1.x; gim[tid][1] = r1.y;
        gre[tid][2] = r2.x; gim[tid][2] = r2.y;
        gre[tid][3] = r3.x; gim[tid][3] = r3.y;
    }
    for (int i = tid; i < DIM; i += 256) {
        vr[slotf(i)] = (i == col) ? 1.0f : 0.0f;
        vi[slotf(i)] = 0.0f;
        int jj = i;
        #pragma unroll
        for (int c = 10; c >= 0; --c) {
            int sc = 10 - c;
            int st = 10 - ((c + 1) % 11);
            jj ^= ((jj >> sc) & 1) << st;
        }
        ptab[i] = (u16)slotf(jj);
    }
    __syncthreads();

    for (int t = tid; t < 400; t += 256) {
        int layer = t / 80, r = t % 80, pair = r / 16, e = r % 16;
        int v = e >> 2, vp = e & 3;
        int a = v >> 1, b = v & 1, ap = vp >> 1, bp = vp & 1;
        int gia = layer * 11 + pair;        // qubit p  (bit 10-p)
        int gib = layer * 11 + 6 + pair;    // qubit p+6 (bit 4-p)
        c32 ga{gre[gia][a*2+ap], gim[gia][a*2+ap]};
        c32 gb{gre[gib][b*2+bp], gim[gib][b*2+bp]};
        c32 pr = cmul(ga, gb);
        G4r[layer][pair][e] = pr.x; G4i[layer][pair][e] = pr.y;
    }
    __syncthreads();

    for (int layer = 0; layer < 5; ++layer) {
        for (int p = 0; p < 5; ++p) {
            const int lo = 4 - p, hi = 10 - p;
            float g4r[16], g4i[16];
            #pragma unroll
            for (int e = 0; e < 16; ++e) {
                g4r[e] = G4r[layer][p][e];
                g4i[e] = G4i[layer][p][e];
            }
            const bool permRead = (layer > 0) && (p == 0);
            if (permRead) {
                float xr[2][4], xi[2][4];
                int es[2][4];
                #pragma unroll
                for (int h = 0; h < 2; ++h) {
                    int g = tid + h * 256;
                    int tmp = ((g >> lo) << (lo + 1)) | (g & ((1 << lo) - 1));
                    int i0  = ((tmp >> hi) << (hi + 1)) | (tmp & ((1 << hi) - 1));
                    #pragma unroll
                    for (int v = 0; v < 4; ++v) {
                        int e = i0 | ((v >> 1) << hi) | ((v & 1) << lo);
                        es[h][v] = slotf(e);
                        int ss = (int)ptab[e];
                        xr[h][v] = vr[ss]; xi[h][v] = vi[ss];
                    }
                }
                __syncthreads();
                #pragma unroll
                for (int h = 0; h < 2; ++h)
                    #pragma unroll
                    for (int v = 0; v < 4; ++v) {
                        float sr = 0.f, si = 0.f;
                        #pragma unroll
                        for (int u = 0; u < 4; ++u) {
                            sr += g4r[v*4+u] * xr[h][u] - g4i[v*4+u] * xi[h][u];
                            si += g4r[v*4+u] * xi[h][u] + g4i[v*4+u] * xr[h][u];
                        }
                        vr[es[h][v]] = sr; vi[es[h][v]] = si;
                    }
                __syncthreads();
            } else {
                #pragma unroll
                for (int h = 0; h < 2; ++h) {
                    int g = tid + h * 256;
                    int tmp = ((g >> lo) << (lo + 1)) | (g & ((1 << lo) - 1));
                    int i0  = ((tmp >> hi) << (hi + 1)) | (tmp & ((1 << hi) - 1));
                    float xr[4], xi[4];
                    int es[4];
                    #pragma unroll
                    for (int v = 0; v < 4; ++v) {
                        int e = i0 | ((v >> 1) << hi) | ((v & 1) << lo);
                        es[v] = slotf(e);
                        xr[v] = vr[es[v]]; xi[v] = vi[es[v]];
                    }
                    #pragma unroll
                    for (int v = 0; v < 4; ++v) {
                        float sr = 0.f, si = 0.f;
                        #pragma unroll
                        for (int u = 0; u < 4; ++u) {
                            sr += g4r[v*4+u] * xr[u] - g4i[v*4+u] * xi[u];
                            si += g4r[v*4+u] * xi[u] + g4i[v*4+u] * xr[u];
                        }
                        vr[es[v]] = sr; vi[es[v]] = si;
                    }
                }
                __syncthreads();
            }
        }
        {
            const int gi = layer * 11 + 5;
            const float g00r = gre[gi][0], g00i = gim[gi][0];
            const float g01r = gre[gi][1], g01i = gim[gi][1];
            const float g10r = gre[gi][2], g10i = gim[gi][2];
            const float g11r = gre[gi][3], g11i = gim[gi][3];
            #pragma unroll
            for (int t = 0; t < 4; ++t) {
                int p2 = tid + t * 256;
                int i0 = ((p2 >> 5) << 6) | (p2 & 31);
                int s0 = slotf(i0), s1 = slotf(i0 + 32);
                float ar = vr[s0], ai = vi[s0];
                float br = vr[s1], bi = vi[s1];
                vr[s0] = g00r*ar - g00i*ai + g01r*br - g01i*bi;
                vi[s0] = g00r*ai + g00i*ar + g01r*bi + g01i*br;
                vr[s1] = g10r*ar - g10i*ai + g11r*br - g11i*bi;
                vi[s1] = g10r*ai + g10i*ar + g11r*bi + g11i*br;
            }
            __syncthreads();
        }
    }
    for (int i = tid; i < DIM; i += 256) {
        ut_re[(size_t)col*DIM + i] = f2bf(vr[slotf(i)]);
        ut_im[(size_t)col*DIM + i] = f2bf(vi[slotf(i)]);
    }
}

// ---------------------------------------------------------------------------
// Kernel 2: bf16 transpose (U^T -> U), 64x64 LDS tiles; z selects re/im.
// ---------------------------------------------------------------------------
__global__ __launch_bounds__(256) void transpose2(const u16* __restrict__ sre,
                                                  const u16* __restrict__ sim,
                                                  u16* __restrict__ dre,
                                                  u16* __restrict__ dim_) {
    const u16* s = blockIdx.z ? sim : sre;
    u16*       d = blockIdx.z ? dim_ : dre;
    __shared__ alignas(16) u16 tile[64][66];
    const int bx = blockIdx.x * 64, by = blockIdx.y * 64;
    for (int e = threadIdx.x; e < 1024; e += 256) {
        int r = e >> 4, c4 = (e & 15) * 4;
        uint2 v = *(const uint2*)(s + (size_t)(by + r) * DIM + bx + c4);
        u16* tp = &tile[r][c4];
        tp[0] = (u16)(v.x); tp[1] = (u16)(v.x >> 16);
        tp[2] = (u16)(v.y); tp[3] = (u16)(v.y >> 16);
    }
    __syncthreads();
    for (int e = threadIdx.x; e < 1024; e += 256) {
        int r = e >> 4, c4 = (e & 15) * 4;
        unsigned lo = (unsigned)tile[c4][r]     | ((unsigned)tile[c4+1][r] << 16);
        unsigned hi = (unsigned)tile[c4+2][r]   | ((unsigned)tile[c4+3][r] << 16);
        *(uint2*)(d + (size_t)(bx + r) * DIM + by + c4) = make_uint2(lo, hi);
    }
}

// ---------------------------------------------------------------------------
// GEMM stage 1 (MFMA, fused, 64x64 tiles, double-buffered):
//   pt[m,n] = sum_k Ure[m,k] X[n,k]; qt with Uim.
// Grid 32x32 = 1024 blocks = 4 blocks/CU (16 waves/CU) -> inter-block latency
// hiding at the barrier drain. LDS 24 KB. 4 waves, wave tile 32x32 (2x2 frags).
// ---------------------------------------------------------------------------
__global__ __launch_bounds__(256, 4) void gemm_stage1(
        const u16* __restrict__ ure, const u16* __restrict__ uim,
        const float* __restrict__ x,
        u16* __restrict__ pt, u16* __restrict__ qt) {
    __shared__ alignas(16) u16 Ar[2][64*32], Ai[2][64*32], Bx[2][64*32];
    const int tid  = threadIdx.x;
    const int lane = tid & 63, w = tid >> 6;
    const int m0 = blockIdx.y * 64, n0 = blockIdx.x * 64;
    const int wm = (w >> 1) * 32, wn = (w & 1) * 32;
    const int ml = lane & 15, quad = lane >> 4;

    f32x4 accP[2][2], accQ[2][2];
    #pragma unroll
    for (int i = 0; i < 2; ++i)
        #pragma unroll
        for (int j = 0; j < 2; ++j) {
            f32x4 z = {0.f, 0.f, 0.f, 0.f};
            accP[i][j] = z; accQ[i][j] = z;
        }

    auto stage = [&](int b, int k0) {
        int ci = tid;                        // 256 chunks of 16B = 64 rows x 32k
        int r = ci >> 2, c = ci & 3;
        size_t goA = ((size_t)(m0 + r) * DIM + k0) * 2 + c * 16;
        gl_lds16((const char*)ure + goA, (char*)Ar[b] + ci * 16);
        gl_lds16((const char*)uim + goA, (char*)Ai[b] + ci * 16);
        const float4* src = (const float4*)(x + (size_t)(n0 + r) * DIM + k0 + c * 8);
        float4 v0 = src[0], v1 = src[1];
        u32x4 pk;
        pk.x = (unsigned)f2bf(v0.x) | ((unsigned)f2bf(v0.y) << 16);
        pk.y = (unsigned)f2bf(v0.z) | ((unsigned)f2bf(v0.w) << 16);
        pk.z = (unsigned)f2bf(v1.x) | ((unsigned)f2bf(v1.y) << 16);
        pk.w = (unsigned)f2bf(v1.z) | ((unsigned)f2bf(v1.w) << 16);
        *(u32x4*)((char*)Bx[b] + ci * 16) = pk;
    };

    stage(0, 0);
    __syncthreads();

    for (int k0 = 0; k0 < DIM; k0 += 32) {
        const int cb = (k0 >> 5) & 1;
        if (k0 + 32 < DIM) stage(cb ^ 1, k0 + 32);   // prefetch next tile

        bf16x8 ar[2], ai[2], bx[2];
        #pragma unroll
        for (int i = 0; i < 2; ++i) {
            ar[i] = *(const bf16x8*)(Ar[cb] + (wm + i*16 + ml) * 32 + quad * 8);
            ai[i] = *(const bf16x8*)(Ai[cb] + (wm + i*16 + ml) * 32 + quad * 8);
            bx[i] = *(const bf16x8*)(Bx[cb] + (wn + i*16 + ml) * 32 + quad * 8);
        }
        #pragma unroll
        for (int i = 0; i < 2; ++i)
            #pragma unroll
            for (int j = 0; j < 2; ++j) {
                accP[i][j] = __builtin_amdgcn_mfma_f32_16x16x32_bf16(ar[i], bx[j], accP[i][j], 0, 0, 0);
                accQ[i][j] = __builtin_amdgcn_mfma_f32_16x16x32_bf16(ai[i], bx[j], accQ[i][j], 0, 0, 0);
            }
        __syncthreads();
    }
    // C/D layout: col = lane&15, row = quad*4 + reg
    #pragma unroll
    for (int i = 0; i < 2; ++i)
        #pragma unroll
        for (int j = 0; j < 2; ++j) {
            int row = m0 + wm + i*16 + quad*4;
            int col = n0 + wn + j*16 + ml;
            #pragma unroll
            for (int r = 0; r < 4; ++r) {
                pt[(size_t)(row + r) * DIM + col] = f2bf(accP[i][j][r]);
                qt[(size_t)(row + r) * DIM + col] = f2bf(accQ[i][j][r]);
            }
        }
}

// ---------------------------------------------------------------------------
// GEMM stage 2 (MFMA, real output, 64x64 tiles, double-buffered):
//   out[m,n] = sum_j Ure[m,j] pt[n,j] + Uim[m,j] qt[n,j] = Re(U X U^H)[m,n]
// LDS 32 KB -> 4 blocks/CU possible (160/32 = 5).
// ---------------------------------------------------------------------------
__global__ __launch_bounds__(256, 4) void gemm_stage2_real(
        const u16* __restrict__ ure, const u16* __restrict__ uim,
        const u16* __restrict__ pt, const u16* __restrict__ qt,
        float* __restrict__ out) {
    __shared__ alignas(16) u16 Ar[2][64*32], Ai[2][64*32], Bp[2][64*32], Bq[2][64*32];
    const int tid  = threadIdx.x;
    const int lane = tid & 63, w = tid >> 6;
    const int m0 = blockIdx.y * 64, n0 = blockIdx.x * 64;
    const int wm = (w >> 1) * 32, wn = (w & 1) * 32;
    const int ml = lane & 15, quad = lane >> 4;

    f32x4 accR[2][2];
    #pragma unroll
    for (int i = 0; i < 2; ++i)
        #pragma unroll
        for (int j = 0; j < 2; ++j) {
            f32x4 z = {0.f, 0.f, 0.f, 0.f};
            accR[i][j] = z;
        }

    auto stage = [&](int b, int k0) {
        int ci = tid;
        int r = ci >> 2, c = ci & 3;
        size_t goA = ((size_t)(m0 + r) * DIM + k0) * 2 + c * 16;
        size_t goB = ((size_t)(n0 + r) * DIM + k0) * 2 + c * 16;
        gl_lds16((const char*)ure + goA, (char*)Ar[b] + ci * 16);
        gl_lds16((const char*)uim + goA, (char*)Ai[b] + ci * 16);
        gl_lds16((const char*)pt  + goB, (char*)Bp[b] + ci * 16);
        gl_lds16((const char*)qt  + goB, (char*)Bq[b] + ci * 16);
    };

    stage(0, 0);
    __syncthreads();

    for (int k0 = 0; k0 < DIM; k0 += 32) {
        const int cb = (k0 >> 5) & 1;
        if (k0 + 32 < DIM) stage(cb ^ 1, k0 + 32);   // prefetch next tile

        bf16x8 ar[2], ai[2], bp[2], bq[2];
        #pragma unroll
        for (int i = 0; i < 2; ++i) {
            ar[i] = *(const bf16x8*)(Ar[cb] + (wm + i*16 + ml) * 32 + quad * 8);
            ai[i] = *(const bf16x8*)(Ai[cb] + (wm + i*16 + ml) * 32 + quad * 8);
            bp[i] = *(const bf16x8*)(Bp[cb] + (wn + i*16 + ml) * 32 + quad * 8);
            bq[i] = *(const bf16x8*)(Bq[cb] + (wn + i*16 + ml) * 32 + quad * 8);
        }
        #pragma unroll
        for (int i = 0; i < 2; ++i)
            #pragma unroll
            for (int j = 0; j < 2; ++j) {
                accR[i][j] = __builtin_amdgcn_mfma_f32_16x16x32_bf16(ar[i], bp[j], accR[i][j], 0, 0, 0);
                accR[i][j] = __builtin_amdgcn_mfma_f32_16x16x32_bf16(ai[i], bq[j], accR[i][j], 0, 0, 0);
            }
        __syncthreads();
    }
    #pragma unroll
    for (int i = 0; i < 2; ++i)
        #pragma unroll
        for (int j = 0; j < 2; ++j) {
            int row = m0 + wm + i*16 + quad*4;
            int col = n0 + wn + j*16 + ml;
            #pragma unroll
            for (int r = 0; r < 4; ++r)
                out[(size_t)(row + r) * DIM + col] = accR[i][j][r];
        }
}

// ---------------------------------------------------------------------------
// Fallback (complex interleaved output) — insurance only, 128x128 1-buf.
// ---------------------------------------------------------------------------
__global__ __launch_bounds__(256, 1) void gemm_stage2_cplx(
        const u16* __restrict__ ure, const u16* __restrict__ uim,
        const u16* __restrict__ pt, const u16* __restrict__ qt,
        float2* __restrict__ out, size_t out_lim) {
    __shared__ alignas(16) u16 Ar[128*32], Ai[128*32], Bp[128*32], Bq[128*32];
    const int tid  = threadIdx.x;
    const int lane = tid & 63, w = tid >> 6;
    const int m0 = blockIdx.y * 128, n0 = blockIdx.x * 128;
    const int wm = (w >> 1) * 64, wn = (w & 1) * 64;
    const int ml = lane & 15, quad = lane >> 4;

    f32x4 accR[4][4], accI[4][4];
    #pragma unroll
    for (int i = 0; i < 4; ++i)
        #pragma unroll
        for (int j = 0; j < 4; ++j) {
            f32x4 z = {0.f, 0.f, 0.f, 0.f};
            accR[i][j] = z; accI[i][j] = z;
        }

    for (int k0 = 0; k0 < DIM; k0 += 32) {
        #pragma unroll
        for (int t = 0; t < 2; ++t) {
            int ci = t * 256 + tid;
            int r = ci >> 2, c = ci & 3;
            size_t goA = ((size_t)(m0 + r) * DIM + k0) * 2 + c * 16;
            size_t goB = ((size_t)(n0 + r) * DIM + k0) * 2 + c * 16;
            gl_lds16((const char*)ure + goA, (char*)Ar + ci * 16);
            gl_lds16((const char*)uim + goA, (char*)Ai + ci * 16);
            gl_lds16((const char*)pt  + goB, (char*)Bp + ci * 16);
            gl_lds16((const char*)qt  + goB, (char*)Bq + ci * 16);
        }
        __syncthreads();
        bf16x8 ar[4], ai[4], bp[4], bq[4];
        #pragma unroll
        for (int i = 0; i < 4; ++i) {
            ar[i] = *(const bf16x8*)(Ar + (wm + i*16 + ml) * 32 + quad * 8);
            ai[i] = *(const bf16x8*)(Ai + (wm + i*16 + ml) * 32 + quad * 8);
            bp[i] = *(const bf16x8*)(Bp + (wn + i*16 + ml) * 32 + quad * 8);
            bq[i] = *(const bf16x8*)(Bq + (wn + i*16 + ml) * 32 + quad * 8);
        }
        #pragma unroll
        for (int i = 0; i < 4; ++i)
            #pragma unroll
            for (int j = 0; j < 4; ++j) {
                accR[i][j] = __builtin_amdgcn_mfma_f32_16x16x32_bf16(ar[i], bp[j], accR[i][j], 0, 0, 0);
                accR[i][j] = __builtin_amdgcn_mfma_f32_16x16x32_bf16(ai[i], bq[j], accR[i][j], 0, 0, 0);
                accI[i][j] = __builtin_amdgcn_mfma_f32_16x16x32_bf16(ai[i], bp[j], accI[i][j], 0, 0, 0);
                f32x4 t2 = __builtin_amdgcn_mfma_f32_16x16x32_bf16(ar[i], bq[j], {0.f,0.f,0.f,0.f}, 0, 0, 0);
                accI[i][j] -= t2;
            }
        __syncthreads();
    }
    #pragma unroll
    for (int i = 0; i < 4; ++i)
        #pragma unroll
        for (int j = 0; j < 4; ++j) {
            int row = m0 + wm + i*16 + quad*4;
            int col = n0 + wn + j*16 + ml;
            #pragma unroll
            for (int r = 0; r < 4; ++r) {
                size_t idx = (size_t)(row + r) * DIM + col;
                if (idx < out_lim)
                    out[idx] = make_float2(accR[i][j][r], accI[i][j][r]);
            }
        }
}

// ---------------------------------------------------------------------------
extern "C" void kernel_launch(void* const* d_in, const int* in_sizes, int n_in,
                              void* d_out, int out_size, void* d_ws, size_t ws_size,
                              hipStream_t stream) {
    int xi = (in_sizes[0] >= in_sizes[1]) ? 0 : 1;
    const float* x = (const float*)d_in[xi];
    const float* w = (const float*)d_in[1 - xi];

    char* ws = (char*)d_ws;
    const size_t P = (size_t)DIM * DIM * 2;   // one bf16 plane = 8 MiB
    if (ws_size < 4 * P) return;

    u16* ut_re = (u16*)(ws);
    u16* ut_im = (u16*)(ws + P);
    u16* u_re  = (u16*)(ws + 2*P);
    u16* u_im  = (u16*)(ws + 3*P);
    u16* pt    = ut_re;   // reuse after transpose
    u16* qt    = ut_im;

    build_ut<<<DIM, 256, 0, stream>>>(w, ut_re, ut_im);
    transpose2<<<dim3(32, 32, 2), 256, 0, stream>>>(ut_re, ut_im, u_re, u_im);
    gemm_stage1<<<dim3(32, 32), 256, 0, stream>>>(u_re, u_im, x, pt, qt);

    if (out_size == DIM * DIM) {
        gemm_stage2_real<<<dim3(32, 32), 256, 0, stream>>>(u_re, u_im, pt, qt,
                                                           (float*)d_out);
    } else {
        gemm_stage2_cplx<<<dim3(16, 16), 256, 0, stream>>>(u_re, u_im, pt, qt,
                                                           (float2*)d_out,
                                                           (size_t)out_size / 2);
    }
}